// Round 7
// baseline (252.800 us; speedup 1.0000x reference)
//
#include <hip/hip_runtime.h>

typedef _Float16 f16;
typedef _Float16 f16x8 __attribute__((ext_vector_type(8)));
typedef float f32x4 __attribute__((ext_vector_type(4)));

#define GLOBAL_AS __attribute__((address_space(1)))
#define LDS_AS __attribute__((address_space(3)))

// async global->LDS. LESSON (R8): LDS dest = wave-uniform base + lane*16 —
// NEVER issue under divergent control flow / per-lane conditional addressing.
// LESSON (R10-R12): A-operand fp32 fusion into GEMM1 is structurally negative.
// LEDGER (R14): ~119 us of every timed iteration is the harness's two 401 MB
// poison fills — subtract before attributing.
// LESSON (R15): swizzle must be re-derived per row width. g^(r&3) on 64B rows
// is a 4-way conflict (rows 0,4,8,12 collide): 4.9M = 25 x 196,608 conflict
// cycles — and the old kernel's 196,608 was its one TAIL32 chunk, same bug.
// For 64B rows use swz(r) = (r&3)^((r>>2)&3): 16-row sweep covers all 8
// bank-start slots exactly twice -> 2 lanes/bank = free.
__device__ __forceinline__ void async16(const void* g, void* l) {
  __builtin_amdgcn_global_load_lds((const GLOBAL_AS unsigned int*)g,
                                   (LDS_AS unsigned int*)l, 16, 0, 0);
}

#define SWZ32(r) (((r) & 3) ^ (((r) >> 2) & 3))

// ---------------- merged conversion kernel (R7/R9-proven; w2o dropped) ----------
// blocks [0,12800):     spikes fp32 [32768][784] -> A16 f16 [32768][800] (pad 0)
// blocks [12800,16000): w_hidden -> w2h (hi pad->800 | lo*2048 pad->1600)
__global__ __launch_bounds__(256) void conv_all(const float* __restrict__ s,
                                                const float* __restrict__ wh,
                                                f16* __restrict__ a16,
                                                f16* __restrict__ w2h) {
  if (blockIdx.x < 12800) {
    int idx = blockIdx.x * 256 + threadIdx.x;  // < 3,276,800
    int m = idx / 100;
    int g = idx - m * 100;
    f16x8 h = {};
    if (g < 98) {
      const float4* p = (const float4*)(s + (size_t)m * 784 + g * 8);
      float4 x = p[0];
      float4 y = p[1];
      h[0] = (f16)x.x; h[1] = (f16)x.y; h[2] = (f16)x.z; h[3] = (f16)x.w;
      h[4] = (f16)y.x; h[5] = (f16)y.y; h[6] = (f16)y.z; h[7] = (f16)y.w;
    }
    *(f16x8*)(a16 + (size_t)m * 800 + g * 8) = h;
  } else {
    int idx = (blockIdx.x - 12800) * 256 + threadIdx.x;
    if (idx < 819200) {
      int h = idx / 1600;
      int c = idx - h * 1600;
      f16 o = (f16)0.f;
      if (c < 784) {
        o = (f16)wh[h * 784 + c];
      } else if (c >= 800 && c < 1584) {
        float x = wh[h * 784 + (c - 800)];
        f16 hi = (f16)x;
        o = (f16)((x - (float)hi) * 2048.0f);  // exact residual, scaled past denormals
      }
      w2h[idx] = o;
    }
  }
}

// ---------------- GEMM1, BK=32, triple-buffered LDS, counted vmcnt (R15) ---------
// c_h[32768][512] = A16[32768][800] x (w2h_hi + 2^-11 w2h_lo)[512][800]^T, f16 out.
// Per chunk: s_barrier (compute c-1 done everywhere -> buf[(c+2)%3] free) ->
// STAGE(c+2) -> vmcnt(12) (chunk c's 6 DMA loads landed; 12 = two chunks in
// flight x 6) -> s_barrier -> compute c. Raw s_barrier, NOT __syncthreads
// (which drains vmcnt(0) and kills the pipeline). Depth-3 gives each chunk's
// loads ~2 compute-phases to land. Last iters re-stage chunk 24 as a uniform
// dummy into an unread buffer (branch-free async16, R8). K=800 = 25*32, no
// tail. LDS 9x8KB = 72 KB -> 2 blocks/CU. Swizzle: slot = g ^ SWZ32(r), free
// (see R15 lesson above). Accumulation order over k unchanged -> c_h bitwise
// identical to R9.
__global__ __launch_bounds__(256, 2) void gemm1_pipe(const f16* __restrict__ A,
                                                     const f16* __restrict__ B,
                                                     f16* __restrict__ C) {
  __shared__ __align__(16) f16 lds_a[3][128 * 32];
  __shared__ __align__(16) f16 lds_bh[3][128 * 32];
  __shared__ __align__(16) f16 lds_bl[3][128 * 32];
  const int t = threadIdx.x;
  const int lane = t & 63;
  const int wave = t >> 6;
  const int b = blockIdx.x;               // 1024 blocks, XCD-grouped
  const int by = (b & 7) + 8 * (b >> 5);  // m-tile
  const int bx = (b >> 3) & 3;            // n-tile: 4 n-blocks of an m-tile share L2
  const int m0 = by * 128;
  const int n0 = bx * 128;
  const int wm = (wave >> 1) * 64;
  const int wn = (wave & 1) * 64;
  const int row = lane & 15;
  const int quad = lane >> 4;

  // per-thread staging slots: j = t + s*256 (s<2), r = j>>2, swizzled granule
  const int j0 = t, j1 = t + 256;
  const int r0 = j0 >> 2, g0 = (j0 & 3) ^ SWZ32(r0);
  const int r1 = j1 >> 2, g1 = (j1 & 3) ^ SWZ32(r1);

  f32x4 acch[4][4] = {};
  f32x4 accl[4][4] = {};

#define STAGE1(c, bi)                                                       \
  {                                                                         \
    const int k0 = (c) * 32;                                                \
    async16(A + (m0 + r0) * 800 + k0 + g0 * 8, &lds_a[bi][j0 * 8]);         \
    async16(A + (m0 + r1) * 800 + k0 + g1 * 8, &lds_a[bi][j1 * 8]);         \
    async16(B + (n0 + r0) * 1600 + k0 + g0 * 8, &lds_bh[bi][j0 * 8]);       \
    async16(B + (n0 + r1) * 1600 + k0 + g1 * 8, &lds_bh[bi][j1 * 8]);       \
    async16(B + (n0 + r0) * 1600 + 800 + k0 + g0 * 8, &lds_bl[bi][j0 * 8]); \
    async16(B + (n0 + r1) * 1600 + 800 + k0 + g1 * 8, &lds_bl[bi][j1 * 8]); \
  }

  STAGE1(0, 0);
  STAGE1(1, 1);
  int ci = 0;  // compute buffer; stage buffer = (ci+2)%3
  for (int c = 0; c < 25; ++c) {
    __builtin_amdgcn_s_barrier();  // compute c-1 done -> buf[(c+2)%3] is free
    const int cn = (c + 2 < 25) ? c + 2 : 24;  // uniform dummy re-stage at the end
    const int si = (ci == 0) ? 2 : ci - 1;     // (c+2)%3
    STAGE1(cn, si);
    asm volatile("s_waitcnt vmcnt(12)" ::: "memory");  // chunk c's 6 loads landed
    __builtin_amdgcn_sched_barrier(0);
    __builtin_amdgcn_s_barrier();  // all waves' chunk-c loads landed -> buf[ci] ready
    const f16* la = lds_a[ci];
    const f16* lbh = lds_bh[ci];
    const f16* lbl = lds_bl[ci];
    f16x8 af[4], bh[4], bl[4];
#pragma unroll
    for (int tm = 0; tm < 4; ++tm) {
      const int ra = wm + tm * 16 + row;
      const int p = quad ^ SWZ32(ra);
      af[tm] = *(const f16x8*)&la[ra * 32 + p * 8];
    }
#pragma unroll
    for (int tn = 0; tn < 4; ++tn) {
      const int rb = wn + tn * 16 + row;
      const int p = quad ^ SWZ32(rb);
      bh[tn] = *(const f16x8*)&lbh[rb * 32 + p * 8];
      bl[tn] = *(const f16x8*)&lbl[rb * 32 + p * 8];
    }
#pragma unroll
    for (int tm = 0; tm < 4; ++tm)
#pragma unroll
      for (int tn = 0; tn < 4; ++tn) {
        acch[tm][tn] =
            __builtin_amdgcn_mfma_f32_16x16x32_f16(af[tm], bh[tn], acch[tm][tn], 0, 0, 0);
        accl[tm][tn] =
            __builtin_amdgcn_mfma_f32_16x16x32_f16(af[tm], bl[tn], accl[tm][tn], 0, 0, 0);
      }
    ci = (ci == 2) ? 0 : ci + 1;
  }
#undef STAGE1

  // C/D layout: col = lane&15, row = quad*4 + r
#pragma unroll
  for (int tm = 0; tm < 4; ++tm)
#pragma unroll
    for (int tn = 0; tn < 4; ++tn)
#pragma unroll
      for (int r = 0; r < 4; ++r) {
        const int mm = m0 + wm + tm * 16 + quad * 4 + r;
        const int nn = n0 + wn + tn * 16 + row;
        C[(size_t)mm * 512 + nn] = (f16)(acch[tm][tn][r] + 4.8828125e-4f * accl[tm][tn][r]);
      }
}

// ---------------- fused LIF + GEMV(w_out) + LI: one block per batch b -----------
// After c_h, the only cross-t coupling is the two scan states; GEMM2 is pointwise
// in t and everything is per-b independent. Block b (512 thr, 8 waves): thread h
// runs neuron h's LIF; per 32-t chunk, spikes go to swizzled LDS, each wave MFMAs
// its 16-o tile against w_out B-fragments preloaded in VGPRs (K=512), co chunk
// lands in padded LDS, threads 0..127 advance LI and store. Eliminates s_h/co
// round-trips, two dispatches, the co f16 rounding, and the LI warm-up approx.
__global__ __launch_bounds__(512, 2) void fused_bgl(const f16* __restrict__ ch,
                                                    const float* __restrict__ wo,
                                                    float* __restrict__ out) {
  const int b = blockIdx.x;   // 0..127
  const int tid = threadIdx.x;
  const int lane = tid & 63;
  const int wave = tid >> 6;  // o-tile index 0..7
  const int trow = lane & 15;
  const int quad = lane >> 4;

  __shared__ __align__(16) f16 s_lds[32 * 512];    // 32 KB, granule-swizzled
  __shared__ __align__(16) float co_lds[32][132];  // 16.9 KB, +4 pad rotates banks

  // B-fragments: o = wave*16 + trow; k(h) = ks*32 + quad*8 + j  (ks=0..15 -> K=512)
  f16x8 bfrag[16];
  {
    const float* wp = wo + (wave * 16 + trow) * 512 + quad * 8;
#pragma unroll
    for (int ks = 0; ks < 16; ++ks) {
      const float4* p = (const float4*)(wp + ks * 32);
      float4 x = p[0];
      float4 y = p[1];
      f16x8 hh;
      hh[0] = (f16)x.x; hh[1] = (f16)x.y; hh[2] = (f16)x.z; hh[3] = (f16)x.w;
      hh[4] = (f16)y.x; hh[5] = (f16)y.y; hh[6] = (f16)y.z; hh[7] = (f16)y.w;
      bfrag[ks] = hh;
    }
  }

  const int h = tid;           // hidden neuron owned by this thread
  float v = 0.f, cur = 0.f;    // LIF state
  float lv = 0.f, lcur = 0.f;  // LI state (valid for tid<128)

  f16 xa[32], xb[32];
#pragma unroll
  for (int j = 0; j < 32; ++j) xa[j] = ch[((size_t)(j * 128 + b)) * 512 + h];

  for (int c = 0; c < 8; ++c) {
    if (c < 7) {
#pragma unroll
      for (int j = 0; j < 32; ++j)
        xb[j] = ch[((size_t)(((c + 1) * 32 + j) * 128 + b)) * 512 + h];
    }
    // LIF 32 steps -> s_lds[t][granule (h>>3)^(t&7)] (2 lanes/bank, conflict-free)
#pragma unroll
    for (int j = 0; j < 32; ++j) {
      float x = (float)xa[j];
      v = v + 0.16666667f * (cur - v);  // v += dt*tau_mem_inv*(-v+i), old i
      cur = 0.8333333f * cur + x;       // i = i*(1-dt*tau_syn_inv) + x
      bool z = v > 1.0f;
      v = z ? 0.f : v;
      s_lds[j * 512 + (((h >> 3) ^ (j & 7)) << 3) + (h & 7)] = z ? (f16)1.f : (f16)0.f;
    }
#pragma unroll
    for (int j = 0; j < 32; ++j) xa[j] = xb[j];
    __syncthreads();

    // MFMA: co[32 t][o-tile(wave)] = s . w_out^T, K=512
    f32x4 acc0 = {};
    f32x4 acc1 = {};
#pragma unroll
    for (int ks = 0; ks < 16; ++ks) {
      const int G = ks * 4 + quad;  // unswizzled k-granule
      f16x8 a0 = *(const f16x8*)&s_lds[trow * 512 + ((G ^ (trow & 7)) << 3)];
      f16x8 a1 = *(const f16x8*)&s_lds[(16 + trow) * 512 + ((G ^ (trow & 7)) << 3)];
      acc0 = __builtin_amdgcn_mfma_f32_16x16x32_f16(a0, bfrag[ks], acc0, 0, 0, 0);
      acc1 = __builtin_amdgcn_mfma_f32_16x16x32_f16(a1, bfrag[ks], acc1, 0, 0, 0);
    }
    // C/D layout: col = lane&15 (=o within tile), row = quad*4 + r (=t within chunk)
#pragma unroll
    for (int r = 0; r < 4; ++r) {
      co_lds[quad * 4 + r][wave * 16 + trow] = acc0[r];
      co_lds[16 + quad * 4 + r][wave * 16 + trow] = acc1[r];
    }
    __syncthreads();

    // LI 32 steps (threads 0..127 = o); other waves proceed to next chunk's LIF —
    // safe: they touch s_lds only, and next co_lds write is behind the next barrier.
    if (tid < 128) {
#pragma unroll
      for (int j = 0; j < 32; ++j) {
        float x = co_lds[j][tid];
        lv = lv + 0.16666667f * (lcur - lv);
        lcur = 0.8333333f * lcur + x;
        out[((size_t)((c * 32 + j) * 128 + b)) * 128 + tid] = lv;
      }
    }
  }
}

// ---------------- launch ----------------
extern "C" void kernel_launch(void* const* d_in, const int* in_sizes, int n_in,
                              void* d_out, int out_size, void* d_ws, size_t ws_size,
                              hipStream_t stream) {
  const float* spikes = (const float*)d_in[0];    // [256][128][784]
  const float* w_hidden = (const float*)d_in[1];  // [512][784]
  const float* w_out = (const float*)d_in[2];     // [128][512]
  float* out = (float*)d_out;                     // [256][128][128]

  char* ws = (char*)d_ws;
  // layout (bytes):
  //   A16  [32768][800] f16 : 52,428,800
  //   w2h  [512][1600]  f16 :  1,638,400
  //   c_h  [32768][512] f16 : 33,554,432
  f16* A16 = (f16*)ws;
  f16* w2h = (f16*)(ws + 52428800);
  f16* c_h = (f16*)(ws + 52428800 + 1638400);

  // merged conversions: spikes->A16 and w_hidden->w2h in one dispatch
  conv_all<<<16000, 256, 0, stream>>>(spikes, w_hidden, A16, w2h);

  // GEMM1 (pipelined, depth-3): c_h = A16 * w2h^T (hi + 2^-11 lo)
  gemm1_pipe<<<1024, 256, 0, stream>>>(A16, w2h, c_h);

  // fused back half: LIF scan + readout GEMV + LI scan, one block per batch b
  fused_bgl<<<128, 512, 0, stream>>>(c_h, w_out, out);
}

// Round 8
// 240.268 us; speedup vs baseline: 1.0522x; 1.0522x over previous
//
#include <hip/hip_runtime.h>

typedef _Float16 f16;
typedef _Float16 f16x8 __attribute__((ext_vector_type(8)));
typedef float f32x4 __attribute__((ext_vector_type(4)));

#define GLOBAL_AS __attribute__((address_space(1)))
#define LDS_AS __attribute__((address_space(3)))

// async global->LDS. LESSON (R8): LDS dest = wave-uniform base + lane*16 —
// NEVER issue under divergent control flow / per-lane conditional addressing
// (schedule-dependent LDS corruption; passed once, diverged under graph replay).
// LESSON (R10-R12): A-operand fusion of fp32->f16 conversion into GEMM1 is
// structurally net-negative in this 2-barrier schedule (reg-staging breaks the
// DMA dataflow: 98-109 us; fp32 DMA doubles the drain: 103 us; baseline 55-61).
// A must enter the GEMM as f16 via a separate memory-bound conversion pass.
// LEDGER (R14): ~119 us of every timed iteration is the harness's two 401 MB
// workspace-poison fills (~60 us each) — subtract them before attributing.
// Controllable budget ~119 us: conv ~26 (HBM floor), gemm1 ~57 (structure
// ceiling), fused_bgl ~5 (serial scan latency), gaps/restores ~30 (fixed).
// LESSON (R15/R16): BK=32 + counted-vmcnt dbuf (66 us) and depth-3 (68.5 us)
// both LOSE to the plain __syncthreads 2-barrier template (~57 us) — consistent
// with the platform record that 2-phase pipelining on 128^2 tiles is null; the
// SQ_LDS_BANK_CONFLICT 4.9M was IDENTICAL under two different XOR swizzles,
// i.e. a fixed per-chunk cost of 64B-row geometry, not a swizzle bug. Gains
// past ~57 us require the full 256^2 8-phase co-designed schedule — not
// attempted under single-shot-per-round risk. This file = proven R5 config.
__device__ __forceinline__ void async16(const void* g, void* l) {
  __builtin_amdgcn_global_load_lds((const GLOBAL_AS unsigned int*)g,
                                   (LDS_AS unsigned int*)l, 16, 0, 0);
}

// ---------------- merged conversion kernel (R7/R9-proven; w2o dropped) ----------
// blocks [0,12800):     spikes fp32 [32768][784] -> A16 f16 [32768][800] (pad 0)
// blocks [12800,16000): w_hidden -> w2h (hi pad->800 | lo*2048 pad->1600)
__global__ __launch_bounds__(256) void conv_all(const float* __restrict__ s,
                                                const float* __restrict__ wh,
                                                f16* __restrict__ a16,
                                                f16* __restrict__ w2h) {
  if (blockIdx.x < 12800) {
    int idx = blockIdx.x * 256 + threadIdx.x;  // < 3,276,800
    int m = idx / 100;
    int g = idx - m * 100;
    f16x8 h = {};
    if (g < 98) {
      const float4* p = (const float4*)(s + (size_t)m * 784 + g * 8);
      float4 x = p[0];
      float4 y = p[1];
      h[0] = (f16)x.x; h[1] = (f16)x.y; h[2] = (f16)x.z; h[3] = (f16)x.w;
      h[4] = (f16)y.x; h[5] = (f16)y.y; h[6] = (f16)y.z; h[7] = (f16)y.w;
    }
    *(f16x8*)(a16 + (size_t)m * 800 + g * 8) = h;
  } else {
    int idx = (blockIdx.x - 12800) * 256 + threadIdx.x;
    if (idx < 819200) {
      int h = idx / 1600;
      int c = idx - h * 1600;
      f16 o = (f16)0.f;
      if (c < 784) {
        o = (f16)wh[h * 784 + c];
      } else if (c >= 800 && c < 1584) {
        float x = wh[h * 784 + (c - 800)];
        f16 hi = (f16)x;
        o = (f16)((x - (float)hi) * 2048.0f);  // exact residual, scaled past denormals
      }
      w2h[idx] = o;
    }
  }
}

// ---------------- f16 MFMA GEMM, BK=64, XOR-swizzled LDS (R4/R9-proven) ------------
// C[M][N_LD] = A[M][K] * B[N][K]^T (+ 2^-11 * A*B_lo^T if B_OFF_LO>0), output OUT.
// LDS: row r holds its 8 16B-granules permuted p = g ^ (r&7): a quad's 16-row
// ds_read_b128 sweep hits all 32 banks (2 lanes/bank = free; R3->R4 fixed 14.3M
// conflicts). XCD_SWZ: 1-D grid of 4*256 blocks, the 4 n-blocks of an m-tile on
// one XCD's L2. __launch_bounds__(256,2) ONLY: (256,3) caps VGPR at 84 and
// spills the 128-VGPR accumulator (R7: 137 us, WRITE_SIZE +46 MB).
template <typename OUT, int N_LD, int A_STRIDE, int B_STRIDE, int NCH64,
          bool TAIL32, int B_OFF_LO, int KSPLIT_SPAN, bool XCD_SWZ>
__global__ __launch_bounds__(256, 2) void gemm_f16(const f16* __restrict__ A,
                                                   const f16* __restrict__ B,
                                                   OUT* __restrict__ C) {
  constexpr bool HAS_LO = (B_OFF_LO > 0);
  __shared__ __align__(16) f16 lds_a[128 * 64];
  __shared__ __align__(16) f16 lds_bh[128 * 64];
  __shared__ __align__(16) f16 lds_bl[HAS_LO ? 128 * 64 : 8];
  const int t = threadIdx.x;
  const int lane = t & 63;
  const int wave = t >> 6;
  int bx, by;
  if (XCD_SWZ) {
    const int b = blockIdx.x;
    by = (b & 7) + 8 * (b >> 5);
    bx = (b >> 3) & 3;
  } else {
    bx = blockIdx.x;
    by = blockIdx.y;
  }
  const int m0 = by * 128;
  const int n0 = KSPLIT_SPAN ? 0 : bx * 128;
  const int kb = KSPLIT_SPAN ? bx * KSPLIT_SPAN : 0;
  OUT* Cp = KSPLIT_SPAN ? C + (size_t)bx * 32768 * N_LD : C;
  const int wm = (wave >> 1) * 64;
  const int wn = (wave & 1) * 64;
  const int row = lane & 15;
  const int quad = lane >> 4;

  f32x4 acch[4][4] = {};
  f32x4 accl[HAS_LO ? 4 : 1][4] = {};

  for (int c = 0; c < NCH64; ++c) {
    const int k0 = kb + c * 64;
#pragma unroll
    for (int s = 0; s < 4; ++s) {
      const int j = t + s * 256;
      const int r = j >> 3;
      const int g = (j & 7) ^ (r & 7);  // xor-swizzled source granule
      async16(A + (m0 + r) * A_STRIDE + k0 + g * 8, &lds_a[j * 8]);
      async16(B + (n0 + r) * B_STRIDE + k0 + g * 8, &lds_bh[j * 8]);
      if (HAS_LO)
        async16(B + (n0 + r) * B_STRIDE + B_OFF_LO + k0 + g * 8, &lds_bl[j * 8]);
    }
    __syncthreads();
#pragma unroll
    for (int ks = 0; ks < 2; ++ks) {
      f16x8 af[4], bh[4], bl[4];
#pragma unroll
      for (int tm = 0; tm < 4; ++tm) {
        const int ra = wm + tm * 16 + row;
        const int p = (ks * 4 + quad) ^ (ra & 7);
        af[tm] = *(const f16x8*)&lds_a[ra * 64 + p * 8];
      }
#pragma unroll
      for (int tn = 0; tn < 4; ++tn) {
        const int rb = wn + tn * 16 + row;
        const int p = (ks * 4 + quad) ^ (rb & 7);
        bh[tn] = *(const f16x8*)&lds_bh[rb * 64 + p * 8];
        if (HAS_LO) bl[tn] = *(const f16x8*)&lds_bl[rb * 64 + p * 8];
      }
#pragma unroll
      for (int tm = 0; tm < 4; ++tm)
#pragma unroll
        for (int tn = 0; tn < 4; ++tn) {
          acch[tm][tn] =
              __builtin_amdgcn_mfma_f32_16x16x32_f16(af[tm], bh[tn], acch[tm][tn], 0, 0, 0);
          if (HAS_LO)
            accl[tm][tn] =
                __builtin_amdgcn_mfma_f32_16x16x32_f16(af[tm], bl[tn], accl[tm][tn], 0, 0, 0);
        }
    }
    __syncthreads();
  }

  if (TAIL32) {  // one 32-wide K tail chunk; rows have 4 granules, swizzle &3
    const int k0 = kb + NCH64 * 64;
#pragma unroll
    for (int s = 0; s < 2; ++s) {
      const int j = t + s * 256;
      const int r = j >> 2;
      const int g = (j & 3) ^ (r & 3);
      async16(A + (m0 + r) * A_STRIDE + k0 + g * 8, &lds_a[j * 8]);
      async16(B + (n0 + r) * B_STRIDE + k0 + g * 8, &lds_bh[j * 8]);
      if (HAS_LO)
        async16(B + (n0 + r) * B_STRIDE + B_OFF_LO + k0 + g * 8, &lds_bl[j * 8]);
    }
    __syncthreads();
    f16x8 af[4], bh[4], bl[4];
#pragma unroll
    for (int tm = 0; tm < 4; ++tm) {
      const int ra = wm + tm * 16 + row;
      const int p = quad ^ (ra & 3);
      af[tm] = *(const f16x8*)&lds_a[ra * 32 + p * 8];
    }
#pragma unroll
    for (int tn = 0; tn < 4; ++tn) {
      const int rb = wn + tn * 16 + row;
      const int p = quad ^ (rb & 3);
      bh[tn] = *(const f16x8*)&lds_bh[rb * 32 + p * 8];
      if (HAS_LO) bl[tn] = *(const f16x8*)&lds_bl[rb * 32 + p * 8];
    }
#pragma unroll
    for (int tm = 0; tm < 4; ++tm)
#pragma unroll
      for (int tn = 0; tn < 4; ++tn) {
        acch[tm][tn] =
            __builtin_amdgcn_mfma_f32_16x16x32_f16(af[tm], bh[tn], acch[tm][tn], 0, 0, 0);
        if (HAS_LO)
          accl[tm][tn] =
              __builtin_amdgcn_mfma_f32_16x16x32_f16(af[tm], bl[tn], accl[tm][tn], 0, 0, 0);
      }
  }

  // C/D layout: col = lane&15, row = quad*4 + r
#pragma unroll
  for (int tm = 0; tm < 4; ++tm)
#pragma unroll
    for (int tn = 0; tn < 4; ++tn)
#pragma unroll
      for (int r = 0; r < 4; ++r) {
        const int mm = m0 + wm + tm * 16 + quad * 4 + r;
        const int nn = n0 + wn + tn * 16 + row;
        float val = acch[tm][tn][r];
        if (HAS_LO) val += 4.8828125e-4f * accl[tm][tn][r];  // 2^-11 exact
        Cp[(size_t)mm * N_LD + nn] = (OUT)val;
      }
}

// ---------------- fused LIF + GEMV(w_out) + LI: one block per batch b -----------
// After c_h, the only cross-t coupling is the two scan states; GEMM2 is pointwise
// in t and everything is per-b independent. Block b (512 thr, 8 waves): thread h
// runs neuron h's LIF; per 32-t chunk, spikes go to swizzled LDS, each wave MFMAs
// its 16-o tile against w_out B-fragments preloaded in VGPRs (K=512), co chunk
// lands in padded LDS, threads 0..127 advance LI and store. Eliminates s_h/co
// round-trips, two dispatches, the co f16 rounding, and the LI warm-up approx.
__global__ __launch_bounds__(512, 2) void fused_bgl(const f16* __restrict__ ch,
                                                    const float* __restrict__ wo,
                                                    float* __restrict__ out) {
  const int b = blockIdx.x;   // 0..127
  const int tid = threadIdx.x;
  const int lane = tid & 63;
  const int wave = tid >> 6;  // o-tile index 0..7
  const int trow = lane & 15;
  const int quad = lane >> 4;

  __shared__ __align__(16) f16 s_lds[32 * 512];    // 32 KB, granule-swizzled
  __shared__ __align__(16) float co_lds[32][132];  // 16.9 KB, +4 pad rotates banks

  // B-fragments: o = wave*16 + trow; k(h) = ks*32 + quad*8 + j  (ks=0..15 -> K=512)
  f16x8 bfrag[16];
  {
    const float* wp = wo + (wave * 16 + trow) * 512 + quad * 8;
#pragma unroll
    for (int ks = 0; ks < 16; ++ks) {
      const float4* p = (const float4*)(wp + ks * 32);
      float4 x = p[0];
      float4 y = p[1];
      f16x8 hh;
      hh[0] = (f16)x.x; hh[1] = (f16)x.y; hh[2] = (f16)x.z; hh[3] = (f16)x.w;
      hh[4] = (f16)y.x; hh[5] = (f16)y.y; hh[6] = (f16)y.z; hh[7] = (f16)y.w;
      bfrag[ks] = hh;
    }
  }

  const int h = tid;           // hidden neuron owned by this thread
  float v = 0.f, cur = 0.f;    // LIF state
  float lv = 0.f, lcur = 0.f;  // LI state (valid for tid<128)

  f16 xa[32], xb[32];
#pragma unroll
  for (int j = 0; j < 32; ++j) xa[j] = ch[((size_t)(j * 128 + b)) * 512 + h];

  for (int c = 0; c < 8; ++c) {
    if (c < 7) {
#pragma unroll
      for (int j = 0; j < 32; ++j)
        xb[j] = ch[((size_t)(((c + 1) * 32 + j) * 128 + b)) * 512 + h];
    }
    // LIF 32 steps -> s_lds[t][granule (h>>3)^(t&7)] (2 lanes/bank, conflict-free)
#pragma unroll
    for (int j = 0; j < 32; ++j) {
      float x = (float)xa[j];
      v = v + 0.16666667f * (cur - v);  // v += dt*tau_mem_inv*(-v+i), old i
      cur = 0.8333333f * cur + x;       // i = i*(1-dt*tau_syn_inv) + x
      bool z = v > 1.0f;
      v = z ? 0.f : v;
      s_lds[j * 512 + (((h >> 3) ^ (j & 7)) << 3) + (h & 7)] = z ? (f16)1.f : (f16)0.f;
    }
#pragma unroll
    for (int j = 0; j < 32; ++j) xa[j] = xb[j];
    __syncthreads();

    // MFMA: co[32 t][o-tile(wave)] = s . w_out^T, K=512
    f32x4 acc0 = {};
    f32x4 acc1 = {};
#pragma unroll
    for (int ks = 0; ks < 16; ++ks) {
      const int G = ks * 4 + quad;  // unswizzled k-granule
      f16x8 a0 = *(const f16x8*)&s_lds[trow * 512 + ((G ^ (trow & 7)) << 3)];
      f16x8 a1 = *(const f16x8*)&s_lds[(16 + trow) * 512 + ((G ^ (trow & 7)) << 3)];
      acc0 = __builtin_amdgcn_mfma_f32_16x16x32_f16(a0, bfrag[ks], acc0, 0, 0, 0);
      acc1 = __builtin_amdgcn_mfma_f32_16x16x32_f16(a1, bfrag[ks], acc1, 0, 0, 0);
    }
    // C/D layout: col = lane&15 (=o within tile), row = quad*4 + r (=t within chunk)
#pragma unroll
    for (int r = 0; r < 4; ++r) {
      co_lds[quad * 4 + r][wave * 16 + trow] = acc0[r];
      co_lds[16 + quad * 4 + r][wave * 16 + trow] = acc1[r];
    }
    __syncthreads();

    // LI 32 steps (threads 0..127 = o); other waves proceed to next chunk's LIF —
    // safe: they touch s_lds only, and next co_lds write is behind the next barrier.
    if (tid < 128) {
#pragma unroll
      for (int j = 0; j < 32; ++j) {
        float x = co_lds[j][tid];
        lv = lv + 0.16666667f * (lcur - lv);
        lcur = 0.8333333f * lcur + x;
        out[((size_t)((c * 32 + j) * 128 + b)) * 128 + tid] = lv;
      }
    }
  }
}

// ---------------- launch ----------------
extern "C" void kernel_launch(void* const* d_in, const int* in_sizes, int n_in,
                              void* d_out, int out_size, void* d_ws, size_t ws_size,
                              hipStream_t stream) {
  const float* spikes = (const float*)d_in[0];    // [256][128][784]
  const float* w_hidden = (const float*)d_in[1];  // [512][784]
  const float* w_out = (const float*)d_in[2];     // [128][512]
  float* out = (float*)d_out;                     // [256][128][128]

  char* ws = (char*)d_ws;
  // layout (bytes):
  //   A16  [32768][800] f16 : 52,428,800
  //   w2h  [512][1600]  f16 :  1,638,400
  //   c_h  [32768][512] f16 : 33,554,432
  f16* A16 = (f16*)ws;
  f16* w2h = (f16*)(ws + 52428800);
  f16* c_h = (f16*)(ws + 52428800 + 1638400);

  // merged conversions: spikes->A16 and w_hidden->w2h in one dispatch
  conv_all<<<16000, 256, 0, stream>>>(spikes, w_hidden, A16, w2h);

  // GEMM1: c_h[32768][512] (f16) = A16[32768][800] * w2h[512][800hi|800lo]^T
  gemm_f16<f16, 512, 800, 1600, 12, true, 800, 0, true>
      <<<1024, 256, 0, stream>>>(A16, w2h, c_h);

  // fused back half: LIF scan + readout GEMV + LI scan, one block per batch b
  fused_bgl<<<128, 512, 0, stream>>>(c_h, w_out, out);
}